// Round 3
// baseline (242.924 us; speedup 1.0000x reference)
//
#include <hip/hip_runtime.h>

// GCN(2 layers, 7 nodes) + linear head + KAN (56 per-feature MLPs) + g-MLP, fused.
// B = 32768. Block = 512 threads = 8 waves, 64 batch elements (lane = elem).
// Each wave owns 7 of the 56 KAN feature nets (k wave-uniform -> weights via s_load).
// Partial g1/lin1 accumulators tree-reduced through LDS.
// LDS: one 58.4 KB union region (y/u, h1/sflat, reduce buffers) -> 2 blocks/CU,
// 16 waves/CU = 50% occupancy (vs 22% in round 1).

#define NB 32768
#define ELEMS 64
#define FS 57            // 56 floats per elem, pad to 57 (odd -> conflict-free)
#define REG (ELEMS * FS) // 3648 floats per reduce slot

__global__ __launch_bounds__(512, 4)
void gcn_kan_fused(const float* __restrict__ x,
                   const int*   __restrict__ edge,
                   const float* __restrict__ gcn1_w, const float* __restrict__ gcn1_b,
                   const float* __restrict__ gcn2_w, const float* __restrict__ gcn2_b,
                   const float* __restrict__ phi_w1, const float* __restrict__ phi_b1,
                   const float* __restrict__ phi_w2, const float* __restrict__ phi_b2,
                   const float* __restrict__ phi_w3, const float* __restrict__ phi_b3,
                   const float* __restrict__ g_w1,   const float* __restrict__ g_b1,
                   const float* __restrict__ g_w2,   const float* __restrict__ g_b2,
                   const float* __restrict__ g_w3,   const float* __restrict__ g_b3,
                   const float* __restrict__ line_w1,const float* __restrict__ line_b1,
                   const float* __restrict__ line_w2,const float* __restrict__ line_b2,
                   float* __restrict__ out)
{
    __shared__ float sU[4 * REG];     // 58368 B union: y/u @slot0, h1/sflat @slot1, red[0..3]
    __shared__ float w1s[128], b1s[8], w2s[64], b2s[8];
    __shared__ float Ahs[49], dinvs[7];

    float* y     = sU;                // [64][57] slot 0
    float* h1    = sU + REG;          // [64][57] slot 1
    float* u     = sU;                // overlays y (y dead)
    float* sflat = sU + REG;          // overlays h1 (h1 dead)

    const int t    = threadIdx.x;
    const int lane = t & 63;
    const int wave = t >> 6;
    const int e0   = blockIdx.x * ELEMS;

    // ---- stage small weights + adjacency identity ----
    if (t < 128) w1s[t] = gcn1_w[t];
    if (t < 64)  w2s[t] = gcn2_w[t];
    if (t < 8)  { b1s[t] = gcn1_b[t]; b2s[t] = gcn2_b[t]; }
    if (t < 49)  Ahs[t] = ((t / 7) == (t % 7)) ? 1.0f : 0.0f;
    __syncthreads();

    // ---- edge scatter (benign duplicate stores of 1.0) ----
    if (t < 14) Ahs[edge[14 + t] * 7 + edge[t]] = 1.0f;   // A[dst][src] = 1

    // ---- Phase A: y = x . W1 per (elem,node); coalesced 64B/thread ----
    if (t < 448) {
        const int e = t / 7, m = t - e * 7;
        const float* xp = x + ((size_t)e0 * 7 + t) * 16;   // e*7+m == t
        float xv[16];
        const float4* xp4 = (const float4*)xp;
        #pragma unroll
        for (int j = 0; j < 4; ++j) {
            float4 v = xp4[j];
            xv[j*4+0] = v.x; xv[j*4+1] = v.y; xv[j*4+2] = v.z; xv[j*4+3] = v.w;
        }
        #pragma unroll
        for (int c = 0; c < 8; ++c) {
            float s = 0.f;
            #pragma unroll
            for (int f = 0; f < 16; ++f) s = fmaf(xv[f], w1s[f * 8 + c], s);
            y[e * FS + m * 8 + c] = s;
        }
    }
    __syncthreads();

    // ---- adjacency normalization ----
    if (t < 7) {
        float s = 0.f;
        #pragma unroll
        for (int m = 0; m < 7; ++m) s += Ahs[t * 7 + m];
        dinvs[t] = rsqrtf(s);
    }
    __syncthreads();
    if (t < 49) Ahs[t] *= dinvs[t / 7] * dinvs[t % 7];
    __syncthreads();

    // ---- Phase C: h1[e][n] = relu(sum_m A[n,m] y[e][m] + b1) ----
    if (t < 448) {
        const int e = t / 7, n = t - e * 7;
        #pragma unroll
        for (int c = 0; c < 8; ++c) {
            float s = b1s[c];
            #pragma unroll
            for (int m = 0; m < 7; ++m)
                s = fmaf(Ahs[n * 7 + m], y[e * FS + m * 8 + c], s);
            h1[e * FS + n * 8 + c] = fmaxf(s, 0.f);
        }
    }
    __syncthreads();   // h1 ready; y dead -> u may overwrite slot 0

    // ---- Phase D1: u[e][m] = h1[e][m] . W2 (same-thread h1) ----
    if (t < 448) {
        const int e = t / 7, m = t - e * 7;
        float hv[8];
        #pragma unroll
        for (int c = 0; c < 8; ++c) hv[c] = h1[e * FS + m * 8 + c];
        #pragma unroll
        for (int o = 0; o < 8; ++o) {
            float s = 0.f;
            #pragma unroll
            for (int c = 0; c < 8; ++c) s = fmaf(hv[c], w2s[c * 8 + o], s);
            u[e * FS + m * 8 + o] = s;
        }
    }
    __syncthreads();

    // ---- Phase D2: sflat[e][n] = relu(sum_m A[n,m] u[e][m] + b2) ----
    if (t < 448) {
        const int e = t / 7, n = t - e * 7;
        #pragma unroll
        for (int o = 0; o < 8; ++o) {
            float s = b2s[o];
            #pragma unroll
            for (int m = 0; m < 7; ++m)
                s = fmaf(Ahs[n * 7 + m], u[e * FS + m * 8 + o], s);
            sflat[e * FS + n * 8 + o] = fmaxf(s, 0.f);
        }
    }
    __syncthreads();

    // ---- Phase E: KAN phi-nets, 7 k's per wave (k wave-uniform -> s_load weights) ----
    float g1a[32];
    #pragma unroll
    for (int j = 0; j < 32; ++j) g1a[j] = 0.f;
    float lina[24];
    #pragma unroll
    for (int j = 0; j < 24; ++j) lina[j] = 0.f;

    const int kbase = __builtin_amdgcn_readfirstlane(wave * 7);
    #pragma unroll 1
    for (int kk = 0; kk < 7; ++kk) {
        const int k = kbase + kk;                 // wave-uniform (SGPR)
        const float f = sflat[lane * FS + k];

        float p1[32];
        #pragma unroll
        for (int i = 0; i < 32; ++i)
            p1[i] = fmaxf(fmaf(f, phi_w1[k * 32 + i], phi_b1[k * 32 + i]), 0.f);

        float p2[32];
        #pragma unroll
        for (int o = 0; o < 32; ++o) p2[o] = phi_b2[k * 32 + o];

        const float* __restrict__ w2k = phi_w2 + k * 1024;
        #pragma unroll 4
        for (int i = 0; i < 32; ++i) {
            const float a = p1[i];
            #pragma unroll
            for (int o = 0; o < 32; ++o)
                p2[o] = fmaf(a, w2k[i * 32 + o], p2[o]);
        }

        float ph = phi_b3[k];
        #pragma unroll
        for (int o = 0; o < 32; ++o)
            ph = fmaf(fmaxf(p2[o], 0.f), phi_w3[k * 32 + o], ph);

        #pragma unroll
        for (int j = 0; j < 32; ++j) g1a[j] = fmaf(ph, g_w1[k * 32 + j], g1a[j]);
        #pragma unroll
        for (int j = 0; j < 24; ++j) lina[j] = fmaf(f, line_w1[k * 24 + j], lina[j]);
    }
    __syncthreads();   // sflat dead; reduce buffers may cover whole union

    // ---- Phase F: tree reduce of 8 wave-partials (56 floats per elem) ----
    // step 1: waves 4..7 write partials to red slots 0..3
    if (wave >= 4) {
        float* my = sU + (wave - 4) * REG + lane * FS;
        #pragma unroll
        for (int j = 0; j < 32; ++j) my[j] = g1a[j];
        #pragma unroll
        for (int j = 0; j < 24; ++j) my[32 + j] = lina[j];
    }
    __syncthreads();
    // step 2: waves 0..3 add their partials into slots 0..3
    if (wave < 4) {
        float* my = sU + wave * REG + lane * FS;
        #pragma unroll
        for (int j = 0; j < 32; ++j) my[j] += g1a[j];
        #pragma unroll
        for (int j = 0; j < 24; ++j) my[32 + j] += lina[j];
    }
    __syncthreads();
    // step 3: 4-way final sum -> slot 0. 64 elems * 56 j's = 3584 sums / 512 thr = 7 each
    {
        const int e = t >> 3, jg = t & 7;
        #pragma unroll
        for (int jj = 0; jj < 7; ++jj) {
            const int j = jg * 7 + jj;
            float s = sU[0 * REG + e * FS + j] + sU[1 * REG + e * FS + j]
                    + sU[2 * REG + e * FS + j] + sU[3 * REG + e * FS + j];
            sU[e * FS + j] = s;
        }
    }
    __syncthreads();

    // ---- Phase G: g-MLP + linear head tail (wave 0, one elem per lane) ----
    if (wave == 0) {
        const float* acc = sU + lane * FS;
        float g1[32];
        #pragma unroll
        for (int j = 0; j < 32; ++j) g1[j] = fmaxf(acc[j] + g_b1[j], 0.f);

        float kan = g_b3[0];
        #pragma unroll
        for (int o = 0; o < 32; ++o) {
            float s = g_b2[o];
            #pragma unroll
            for (int i = 0; i < 32; ++i) s = fmaf(g1[i], g_w2[i * 32 + o], s);
            kan = fmaf(fmaxf(s, 0.f), g_w3[o], kan);
        }

        float lin = line_b2[0];
        #pragma unroll
        for (int j = 0; j < 24; ++j)
            lin = fmaf(fmaxf(acc[32 + j] + line_b1[j], 0.f), line_w2[j], lin);

        out[e0 + lane] = 0.5f * (lin + kan);
    }
}

extern "C" void kernel_launch(void* const* d_in, const int* in_sizes, int n_in,
                              void* d_out, int out_size, void* d_ws, size_t ws_size,
                              hipStream_t stream) {
    const float* x       = (const float*)d_in[0];
    const int*   edge    = (const int*)  d_in[1];
    const float* gcn1_w  = (const float*)d_in[2];
    const float* gcn1_b  = (const float*)d_in[3];
    const float* gcn2_w  = (const float*)d_in[4];
    const float* gcn2_b  = (const float*)d_in[5];
    const float* phi_w1  = (const float*)d_in[6];
    const float* phi_b1  = (const float*)d_in[7];
    const float* phi_w2  = (const float*)d_in[8];
    const float* phi_b2  = (const float*)d_in[9];
    const float* phi_w3  = (const float*)d_in[10];
    const float* phi_b3  = (const float*)d_in[11];
    const float* g_w1    = (const float*)d_in[12];
    const float* g_b1    = (const float*)d_in[13];
    const float* g_w2    = (const float*)d_in[14];
    const float* g_b2    = (const float*)d_in[15];
    const float* g_w3    = (const float*)d_in[16];
    const float* g_b3    = (const float*)d_in[17];
    const float* line_w1 = (const float*)d_in[18];
    const float* line_b1 = (const float*)d_in[19];
    const float* line_w2 = (const float*)d_in[20];
    const float* line_b2 = (const float*)d_in[21];
    float* out = (float*)d_out;

    dim3 grid(NB / ELEMS);   // 512 blocks
    dim3 block(512);         // 8 waves
    gcn_kan_fused<<<grid, block, 0, stream>>>(
        x, edge, gcn1_w, gcn1_b, gcn2_w, gcn2_b,
        phi_w1, phi_b1, phi_w2, phi_b2, phi_w3, phi_b3,
        g_w1, g_b1, g_w2, g_b2, g_w3, g_b3,
        line_w1, line_b1, line_w2, line_b2, out);
}